// Round 4
// baseline (82.138 us; speedup 1.0000x reference)
//
#include <hip/hip_runtime.h>
#include <math.h>

// Problem constants (from reference): B=8, C=4, H=256, W=256 -> 32 images.
#define NIMG 32
#define H 256
#define W 256
#define RWIN 16     // envelope search radius (exactness via fallback)
#define PROWS 96    // staged g2 rows per panel (64 outputs + 2*RWIN halo)

// ---------------------------------------------------------------------------
// Row transform: exact 1D distance-to-nearest-zero (squared) for one full
// 256-px row, computed by one wave (64 lanes x float4) with shuffle scans.
// Returns this lane's 4 squared distances. k (the row) is wave-uniform.
// ---------------------------------------------------------------------------
__device__ __forceinline__ float4 row_scan_g2(const float* __restrict__ xrow,
                                              int lane) {
    const float4 v = reinterpret_cast<const float4*>(xrow)[lane];
    const int base = lane * 4;

    // Background = (x == 0.0f). NaN != 0 -> foreground (matches reference).
    bool bgs[4];
    bgs[0] = (v.x == 0.0f);
    bgs[1] = (v.y == 0.0f);
    bgs[2] = (v.z == 0.0f);
    bgs[3] = (v.w == 0.0f);

    // last background index <= each position: wave max-prefix-scan
    int lanelast = -1;
    #pragma unroll
    for (int e = 0; e < 4; ++e) if (bgs[e]) lanelast = base + e;
    int s = lanelast;
    #pragma unroll
    for (int off = 1; off < 64; off <<= 1) {
        int t = __shfl_up(s, off);
        if (lane >= off) s = max(s, t);
    }
    int excl_last = __shfl_up(s, 1);
    if (lane == 0) excl_last = -1;

    // first background index >= each position: wave min-suffix-scan
    const int BIG = 1 << 29;
    int lanefirst = BIG;
    #pragma unroll
    for (int e = 3; e >= 0; --e) if (bgs[e]) lanefirst = base + e;
    int s2 = lanefirst;
    #pragma unroll
    for (int off = 1; off < 64; off <<= 1) {
        int t = __shfl_down(s2, off);
        if (lane + off < 64) s2 = min(s2, t);
    }
    int excl_first = __shfl_down(s2, 1);
    if (lane == 63) excl_first = BIG;

    float dl[4], dr[4];
    int cur = excl_last;
    #pragma unroll
    for (int e = 0; e < 4; ++e) {
        int w = base + e;
        if (bgs[e]) { dl[e] = 0.0f; cur = w; }
        else        { dl[e] = (cur < 0) ? 1.0e6f : (float)(w - cur); }
    }
    int cur2 = excl_first;
    #pragma unroll
    for (int e = 3; e >= 0; --e) {
        int w = base + e;
        if (bgs[e]) { dr[e] = 0.0f; cur2 = w; }
        else        { dr[e] = (cur2 >= BIG) ? 1.0e6f : (float)(cur2 - w); }
    }

    float4 o; float a;
    a = fminf(dl[0], dr[0]); o.x = a * a;
    a = fminf(dl[1], dr[1]); o.y = a * a;
    a = fminf(dl[2], dr[2]); o.z = a * a;
    a = fminf(dl[3], dr[3]); o.w = a * a;
    return o;
}

// Stage PROWS rows (kb .. kb+95, OOB rows = sentinel) of row-transform g2,
// keeping the 64-col slice [c0, c0+64), into sg2[96][64]. Rows distributed
// across the block's 4 waves, two per iteration for scan-chain ILP.
__device__ __forceinline__ void stage_chunk(float* __restrict__ sg2,
                                            const float* __restrict__ ximg,
                                            int kb, int c0, int lane, int wv) {
    const int wcol    = lane * 4 - c0;
    const bool writer = (wcol >= 0) && (wcol < 64);
    #pragma unroll
    for (int j = 0; j < PROWS / 8; ++j) {          // 12 iters, 2 rows each
        const int r0 = wv + 4 * (2 * j);
        const int r1 = wv + 4 * (2 * j + 1);
        const int k0 = kb + r0, k1 = kb + r1;
        float4 g0 = make_float4(1.0e12f, 1.0e12f, 1.0e12f, 1.0e12f);
        float4 g1 = g0;
        if (k0 >= 0 && k0 < H) g0 = row_scan_g2(ximg + (size_t)k0 * W, lane);
        if (k1 >= 0 && k1 < H) g1 = row_scan_g2(ximg + (size_t)k1 * W, lane);
        if (writer) {
            *reinterpret_cast<float4*>(&sg2[r0 * 64 + wcol]) = g0;
            *reinterpret_cast<float4*>(&sg2[r1 * 64 + wcol]) = g1;
        }
    }
}

// ---------------------------------------------------------------------------
// Fused exact EDT: block = (image, 64-row output tile, 64-col tile).
// Recomputes the row transform for its 96-row halo panel (no workspace),
// windowed +-RWIN column envelope, chunked full-rescan fallback for
// exactness on adversarial inputs, sqrt + NaN passthrough on store.
// ---------------------------------------------------------------------------
__global__ __launch_bounds__(256) void edt_fused(const float* __restrict__ x,
                                                 float* __restrict__ out) {
    __shared__ float sg2[PROWS * 64];   // 24 KB

    const int b    = blockIdx.x;        // 0..511
    const int img  = b >> 4;
    const int rem  = b & 15;
    const int i0   = (rem >> 2) * 64;   // output row tile base
    const int c0   = (rem & 3) * 64;    // column tile base
    const int lane = threadIdx.x & 63;
    const int wv   = threadIdx.x >> 6;

    const float* ximg = x + (size_t)img * (H * W);

    stage_chunk(sg2, ximg, i0 - RWIN, c0, lane, wv);
    __syncthreads();

    const int c     = lane;             // column within tile
    const int ig    = wv;
    const int ibase = i0 + ig * 16;

    float best[16];
    #pragma unroll
    for (int m = 0; m < 16; ++m) best[m] = 3.0e38f;

    // Windowed pass: srow = ig*16 + t, t in [0,48); i - k = (m + RWIN) - t.
    const int srow0 = ig * 16;
    #pragma unroll 4
    for (int t = 0; t < 2 * RWIN + 16; ++t) {
        float ld = sg2[(srow0 + t) * 64 + c];   // 2-way bank alias: free
        float dt = (float)(RWIN - t);
        #pragma unroll
        for (int m = 0; m < 16; ++m) {
            float diff = dt + (float)m;
            best[m] = fminf(best[m], fmaf(diff, diff, ld));
        }
    }

    // Exactness: outside the window (i-k)^2 >= (RWIN+1)^2 = 289.
    const float thr = (float)((RWIN + 1) * (RWIN + 1));
    bool needExt = false;
    #pragma unroll
    for (int m = 0; m < 16; ++m) needExt |= (best[m] > thr);

    if (__syncthreads_count(needExt ? 1 : 0) != 0) {
        // Rare exact fallback: re-stage the full column range in 3 chunks.
        for (int kb = 0; kb < H; kb += PROWS) {     // 0, 96, 192
            __syncthreads();                         // prior reads complete
            stage_chunk(sg2, ximg, kb, c0, lane, wv);
            __syncthreads();
            #pragma unroll 4
            for (int t = 0; t < PROWS; ++t) {
                float ld = sg2[t * 64 + c];
                float dk = (float)(ibase - (kb + t));
                #pragma unroll
                for (int m = 0; m < 16; ++m) {
                    float diff = dk + (float)m;
                    best[m] = fminf(best[m], fmaf(diff, diff, ld));
                }
            }
        }
    }

    const int ocol = c0 + c;
    #pragma unroll
    for (int m = 0; m < 16; ++m) {
        int i      = ibase + m;
        size_t idx = (size_t)img * (H * W) + (size_t)i * W + ocol;
        float xv   = x[idx];                 // L2-warm re-read for NaN check
        out[idx]   = (xv != xv) ? xv : sqrtf(best[m]);
    }
}

extern "C" void kernel_launch(void* const* d_in, const int* in_sizes, int n_in,
                              void* d_out, int out_size, void* d_ws, size_t ws_size,
                              hipStream_t stream) {
    const float* x = (const float*)d_in[0];
    float* out     = (float*)d_out;
    (void)d_ws; (void)ws_size;

    // 32 images * 4 col-tiles * 4 row-tiles = 512 blocks, 2 per CU.
    edt_fused<<<dim3(NIMG * 16), dim3(256), 0, stream>>>(x, out);
}

// Round 5
// 77.410 us; speedup vs baseline: 1.0611x; 1.0611x over previous
//
#include <hip/hip_runtime.h>
#include <math.h>

// Problem constants (from reference): B=8, C=4, H=256, W=256 -> 32 images.
#define NIMG 32
#define H 256
#define W 256
#define RWIN 16                  // envelope search radius (exactness via fallback)
#define PANEL_ROWS (64 + 2*RWIN) // 96 staged g2 rows per 64-row output tile

// Best-measured configuration (round 2: 78.2 us, absmax 0). Timed region is
// dominated by harness resets (256 MiB ws poison = ~43 us @ ~78% HBM peak +
// ~25 us fixed reset/gap overhead); kernel-side contribution ~8 us.

// ---------------------------------------------------------------------------
// Kernel 1: per-row 1D distance to nearest background (x==0) pixel, squared.
// One wave (64 lanes) per row; each lane owns 4 contiguous pixels (float4).
// ---------------------------------------------------------------------------
__global__ __launch_bounds__(256) void edt_rows(const float* __restrict__ x,
                                                float* __restrict__ g2) {
    const int lane = threadIdx.x & 63;
    const int wv   = threadIdx.x >> 6;
    const int row  = blockIdx.x * 4 + wv;          // 0 .. NIMG*H-1

    const float4 v = reinterpret_cast<const float4*>(x + (size_t)row * W)[lane];
    const int base = lane * 4;

    // Background = (x == 0.0f). NaN != 0 -> foreground (matches reference mask).
    bool bgs[4];
    bgs[0] = (v.x == 0.0f);
    bgs[1] = (v.y == 0.0f);
    bgs[2] = (v.z == 0.0f);
    bgs[3] = (v.w == 0.0f);

    // --- last background index within this lane's 4 elems (-1 = none) ---
    int lanelast = -1;
    #pragma unroll
    for (int e = 0; e < 4; ++e) if (bgs[e]) lanelast = base + e;

    int s = lanelast;
    #pragma unroll
    for (int off = 1; off < 64; off <<= 1) {
        int t = __shfl_up(s, off);
        if (lane >= off) s = max(s, t);
    }
    int excl_last = __shfl_up(s, 1);
    if (lane == 0) excl_last = -1;

    // --- first background index within this lane's 4 elems (BIG = none) ---
    const int BIG = 1 << 29;
    int lanefirst = BIG;
    #pragma unroll
    for (int e = 3; e >= 0; --e) if (bgs[e]) lanefirst = base + e;

    int s2 = lanefirst;
    #pragma unroll
    for (int off = 1; off < 64; off <<= 1) {
        int t = __shfl_down(s2, off);
        if (lane + off < 64) s2 = min(s2, t);
    }
    int excl_first = __shfl_down(s2, 1);
    if (lane == 63) excl_first = BIG;

    float dl[4], dr[4];
    int cur = excl_last;
    #pragma unroll
    for (int e = 0; e < 4; ++e) {
        int w = base + e;
        if (bgs[e]) { dl[e] = 0.0f; cur = w; }
        else        { dl[e] = (cur < 0) ? 1.0e6f : (float)(w - cur); }
    }
    int cur2 = excl_first;
    #pragma unroll
    for (int e = 3; e >= 0; --e) {
        int w = base + e;
        if (bgs[e]) { dr[e] = 0.0f; cur2 = w; }
        else        { dr[e] = (cur2 >= BIG) ? 1.0e6f : (float)(cur2 - w); }
    }

    float4 o;
    float a;
    a = fminf(dl[0], dr[0]); o.x = a * a;
    a = fminf(dl[1], dr[1]); o.y = a * a;
    a = fminf(dl[2], dr[2]); o.z = a * a;
    a = fminf(dl[3], dr[3]); o.w = a * a;
    reinterpret_cast<float4*>(g2 + (size_t)row * W)[lane] = o;
}

// ---------------------------------------------------------------------------
// Kernel 2: per-column lower envelope D2[i,j] = min_k (i-k)^2 + g2[k,j], sqrt.
// Block = 256 threads handles one (image, 64-col tile, 64-row output tile).
// Windowed exact scan: only k in [i-RWIN, i+RWIN] can matter when
// best <= (RWIN+1)^2 (since (i-k)^2 alone >= (RWIN+1)^2 outside). A block-wide
// fallback to a full 256-scan (from global, L2/L3-resident) preserves
// exactness for adversarial inputs. Staged panel: 96 rows x 64 cols = 24 KB
// -> 6 blocks/CU occupancy.
// ---------------------------------------------------------------------------
__global__ __launch_bounds__(256) void edt_cols(const float* __restrict__ g2,
                                                const float* __restrict__ x,
                                                float* __restrict__ out) {
    __shared__ float sg2[PANEL_ROWS * 64];   // 24 KB

    const int b    = blockIdx.x;        // 0..511
    const int img  = b >> 4;
    const int rem  = b & 15;
    const int i0   = (rem >> 2) * 64;   // output row tile base
    const int c0   = (rem & 3) * 64;    // column tile base

    const float* gbase = g2 + (size_t)img * (H * W) + c0;

    // Stage panel rows k = i0-RWIN .. i0+63+RWIN (clamped; OOB = sentinel).
    for (int idx = threadIdx.x; idx < PANEL_ROWS * 64; idx += 256) {
        int srow = idx >> 6;
        int c    = idx & 63;
        int k    = i0 - RWIN + srow;
        float vk = (k >= 0 && k < H) ? gbase[(size_t)k * W + c] : 1.0e12f;
        sg2[idx] = vk;
    }
    __syncthreads();

    const int c     = threadIdx.x & 63;
    const int ig    = threadIdx.x >> 6;
    const int ibase = i0 + ig * 16;

    float best[16];
    #pragma unroll
    for (int m = 0; m < 16; ++m) best[m] = 3.0e38f;

    // Window: k = ibase-RWIN .. ibase+15+RWIN  (48 iters), i.e.
    // srow = ig*16 + t, t in [0,48); i - k = (m + RWIN) - t.
    const int srow0 = ig * 16;
    #pragma unroll 4
    for (int t = 0; t < 2 * RWIN + 16; ++t) {
        float ld = sg2[(srow0 + t) * 64 + c];   // 2-way bank alias: free
        float dt = (float)(RWIN - t);
        #pragma unroll
        for (int m = 0; m < 16; ++m) {
            float diff = dt + (float)m;
            best[m] = fminf(best[m], fmaf(diff, diff, ld));
        }
    }

    // Exactness check: outside the window (i-k)^2 >= (RWIN+1)^2.
    const float thr = (float)((RWIN + 1) * (RWIN + 1));
    bool needExt = false;
    #pragma unroll
    for (int m = 0; m < 16; ++m) needExt |= (best[m] > thr);

    if (__syncthreads_count(needExt ? 1 : 0) != 0) {
        // Rare exact-fallback: full 256-row scan from global (L2/L3 resident).
        #pragma unroll 4
        for (int k = 0; k < H; ++k) {
            float ld = gbase[(size_t)k * W + c];
            float dk = (float)(ibase - k);
            #pragma unroll
            for (int m = 0; m < 16; ++m) {
                float diff = dk + (float)m;
                best[m] = fminf(best[m], fmaf(diff, diff, ld));
            }
        }
    }

    const int ocol = c0 + c;
    #pragma unroll
    for (int m = 0; m < 16; ++m) {
        int i   = ibase + m;
        size_t idx = (size_t)img * (H * W) + (size_t)i * W + ocol;
        float xv = x[idx];
        out[idx] = (xv != xv) ? xv : sqrtf(best[m]);
    }
}

extern "C" void kernel_launch(void* const* d_in, const int* in_sizes, int n_in,
                              void* d_out, int out_size, void* d_ws, size_t ws_size,
                              hipStream_t stream) {
    const float* x  = (const float*)d_in[0];
    float* out      = (float*)d_out;
    float* g2       = (float*)d_ws;   // NIMG*H*W floats = 8.4 MB scratch

    // Kernel 1: 32*256 = 8192 rows, 4 rows (waves) per block.
    edt_rows<<<dim3((NIMG * H) / 4), dim3(256), 0, stream>>>(x, g2);

    // Kernel 2: 32 images * 4 col-tiles * 4 row-tiles = 512 blocks.
    edt_cols<<<dim3(NIMG * 16), dim3(256), 0, stream>>>(g2, x, out);
}